// Round 11
// baseline (169.633 us; speedup 1.0000x reference)
//
#include <hip/hip_runtime.h>

#define B_    2
#define T_    2048
#define C_    1024
#define H_    16
#define DH_   64
#define M_    (B_ * T_)        // 4096 tokens
#define NQKV  (3 * C_)         // 3072

typedef __bf16 bf16;
typedef __bf16 bf16x2 __attribute__((ext_vector_type(2)));
typedef __bf16 bf16x4 __attribute__((ext_vector_type(4)));
typedef __bf16 bf16x8 __attribute__((ext_vector_type(8)));
typedef float  f32x4  __attribute__((ext_vector_type(4)));
typedef float  f32x16 __attribute__((ext_vector_type(16)));
typedef unsigned u32x4 __attribute__((ext_vector_type(4)));

// async global->LDS, 16B per lane (global_load_lds_dwordx4).
__device__ __forceinline__ void async16(const void* g, void* l) {
  __builtin_amdgcn_global_load_lds(
      (const __attribute__((address_space(1))) void*)g,
      (__attribute__((address_space(3))) void*)l, 16, 0, 0);
}

// pack two f32 -> one dword of 2 bf16 (lo in bits 0-15)
__device__ __forceinline__ unsigned pk(float a, float b) {
  bf16x2 t; t[0] = (bf16)a; t[1] = (bf16)b;
  return __builtin_bit_cast(unsigned, t);
}

// ---------------------------------------------------------------- fused prep
__global__ __launch_bounds__(256) void prep_k(
    const float* __restrict__ x, bf16* __restrict__ xbf,
    const float* __restrict__ Wqkv, bf16* __restrict__ wqkvT,
    const float* __restrict__ Wproj, bf16* __restrict__ wprojT) {
  __shared__ float tile[32][33];
  const int bid = blockIdx.x;
  if (bid < 4096) {                              // ---- cvt x
    const int i = (bid * 256 + threadIdx.x) * 4;
    float4 v = *(const float4*)(x + i);
    bf16x4 o;
    o[0] = (bf16)v.x; o[1] = (bf16)v.y; o[2] = (bf16)v.z; o[3] = (bf16)v.w;
    *(bf16x4*)(xbf + i) = o;
    return;
  }
  const float* in; bf16* out; int R, C, cb, rb;
  if (bid < 4096 + 3072) {                       // ---- Wqkv [1024 x 3072]
    const int b = bid - 4096;
    in = Wqkv; out = wqkvT; R = 1024; C = 3072; cb = b % 96; rb = b / 96;
  } else {                                       // ---- Wproj [1024 x 1024]
    const int b = bid - 7168;
    in = Wproj; out = wprojT; R = 1024; C = 1024; cb = b & 31; rb = b >> 5;
  }
  const int c0 = cb * 32, r0 = rb * 32;
  const int tx = threadIdx.x & 31, ty = threadIdx.x >> 5;
#pragma unroll
  for (int j = 0; j < 4; j++)
    tile[ty + j * 8][tx] = in[(size_t)(r0 + ty + j * 8) * C + c0 + tx];
  __syncthreads();
#pragma unroll
  for (int j = 0; j < 4; j++)
    out[(size_t)(c0 + ty + j * 8) * R + r0 + tx] = (bf16)tile[tx][ty + j * 8];
}

// ---------------------------------------------------------------- GEMM
// C[M,N] = A[M,K=1024] * Bt[N,K]^T (+bias). Tile BM x BN, BK=64, 4 waves.
// r11: T1 XCD-aware bijective block swizzle (nwg%8==0 for both grids).
// sbid = (bid&7)*(NWG/8) + (bid>>3); m_idx = sbid%GX, n_idx = sbid/GX ->
// each XCD gets an exclusive contiguous run of B-panels (QKV: 3 panels/XCD,
// B re-fetch 48MB -> 6MB; proj: 2/XCD). A traffic unchanged.
template <int EPI, int BM, int BN, int MW, int GX, int NWG>
__global__ __launch_bounds__(256, MW) void gemm_k(
    const bf16* __restrict__ A, const bf16* __restrict__ Bt,
    const float* __restrict__ bias, float* __restrict__ outF,
    bf16* __restrict__ qb, bf16* __restrict__ kb, bf16* __restrict__ vtb) {
  constexpr int K = 1024;
  constexpr int MI = BM / 32;
  constexpr int NJ = BN / 32;
  __shared__ alignas(16) bf16 As[BM * 64];
  __shared__ alignas(16) bf16 Bs[BN * 64];
  const int tid = threadIdx.x;
  const int lane = tid & 63, wv = tid >> 6;
  const int l15 = lane & 15, quad = lane >> 4;
  const int wm = (wv >> 1) * (BM / 2), wn = (wv & 1) * (BN / 2);

  // T1 XCD swizzle (bijective: NWG % 8 == 0)
  const int bid = blockIdx.y * GX + blockIdx.x;
  const int sbid = (bid & 7) * (NWG / 8) + (bid >> 3);
  const int m0 = (sbid % GX) * BM, n0 = (sbid / GX) * BN;

  f32x4 acc[MI][NJ] = {};

  const int srow = tid >> 3;
  const int sgb = ((tid & 7) ^ (srow & 7)) * 8;
  const bf16* ga = A + (size_t)(m0 + srow) * K + sgb;
  const bf16* gb = Bt + (size_t)(n0 + srow) * K + sgb;
  const int swz = l15 & 7;

  for (int it = 0; it < K / 64; ++it) {
    const int k0 = it * 64;
#pragma unroll
    for (int c = 0; c < BM / 32; c++)
      async16(ga + k0 + (size_t)(c * 32) * K, As + tid * 8 + c * 2048);
#pragma unroll
    for (int c = 0; c < BN / 32; c++)
      async16(gb + k0 + (size_t)(c * 32) * K, Bs + tid * 8 + c * 2048);
    __syncthreads();
    bf16x8 af[2][MI], bfr[2][NJ];
#pragma unroll
    for (int kk = 0; kk < 2; kk++) {
#pragma unroll
      for (int i = 0; i < MI; i++)
        af[kk][i] = *(const bf16x8*)(As + (wm + i * 16 + l15) * 64 +
                                     (((kk * 4 + quad) ^ swz) << 3));
#pragma unroll
      for (int j = 0; j < NJ; j++)
        bfr[kk][j] = *(const bf16x8*)(Bs + (wn + j * 16 + l15) * 64 +
                                      (((kk * 4 + quad) ^ swz) << 3));
    }
#pragma unroll
    for (int kk = 0; kk < 2; kk++)
#pragma unroll
      for (int i = 0; i < MI; i++)
#pragma unroll
        for (int j = 0; j < NJ; j++)
          acc[i][j] = __builtin_amdgcn_mfma_f32_16x16x32_bf16(
              af[kk][i], bfr[kk][j], acc[i][j], 0, 0, 0);
    __syncthreads();
  }

#pragma unroll
  for (int i = 0; i < MI; i++) {
#pragma unroll
    for (int j = 0; j < NJ; j++) {
      const int gcol = n0 + wn + j * 16 + l15;
      const float bv = bias[gcol];
      const int trow = m0 + wm + i * 16 + quad * 4;
      if constexpr (EPI == 0) {
        const int which = gcol >> 10;
        const int hn = gcol & 1023;
        const int h = hn >> 6, d = hn & 63;
        const int bb = trow >> 11, t = trow & 2047;
        const int head = bb * 16 + h;
        if (which == 0) {
#pragma unroll
          for (int r = 0; r < 4; r++)
            qb[head * 131072 + (t + r) * 64 + d] =
                (bf16)((acc[i][j][r] + bv) * 0.1803368801f); // 1/8 * log2(e)
        } else if (which == 1) {
#pragma unroll
          for (int r = 0; r < 4; r++)
            kb[head * 131072 + (t + r) * 64 + d] = (bf16)(acc[i][j][r] + bv);
        } else {
          bf16x4 pv;
#pragma unroll
          for (int r = 0; r < 4; r++) pv[r] = (bf16)(acc[i][j][r] + bv);
          *(bf16x4*)(vtb + head * 131072 + d * 2048 + t) = pv;
        }
      } else {
#pragma unroll
        for (int r = 0; r < 4; r++)
          outF[(size_t)(trow + r) * 1024 + gcol] = acc[i][j][r] + bv;
      }
    }
  }
}

// ---------------------------------------------------------------- flash attention
// (r10 uniform-wall pair blocks, unchanged — frozen. Post-r10 note: FOUR
// structurally distinct attn kernels (r2/r4/r9/r10) all measure 46.5-47.4us
// across 8-16 waves/CU, 9-16 serial iters, 2x LDS-traffic differences, with
// all pipes <30%. Structural rewrites exhausted; plateau accepted.)
__global__ __launch_bounds__(512, 2) void attn_k(const bf16* __restrict__ Q,
                                                 const bf16* __restrict__ K,
                                                 const bf16* __restrict__ Vt,
                                                 bf16* __restrict__ O) {
  __shared__ alignas(16) bf16 Ks[2][2][128 * 64]; // [grp][buf][kt][d]  64KB
  __shared__ alignas(16) bf16 Vs[2][2][64 * 128]; // [grp][buf][d][kt]  64KB
  const int tid = threadIdx.x, lane = tid & 63, wv = tid >> 6;  // wv 0..7
  const int l31 = lane & 31, hi = lane >> 5;
  const int grp = wv >> 2, qs = wv & 3;          // group / q sub-block
  const int gt = tid & 255;                      // intra-group thread

  const int b = blockIdx.x;                      // 0..255
  const int bh = (b & 7) | (((b >> 3) & 3) << 3);  // head 0..31, b&7 = XCD
  const int p = b >> 5;                          // pair index 0..7
  const int jA = p, jB = 15 - p;

  const bf16* Qb = Q + (size_t)bh * 131072;
  const bf16* Kb = K + (size_t)bh * 131072;
  const bf16* Vb = Vt + (size_t)bh * 131072;

  const bf16* gk = Kb + (gt >> 3) * 64 + ((gt & 7) ^ ((gt >> 3) & 7)) * 8;
  const bf16* gv = Vb + (gt >> 4) * 2048 + ((gt & 15) ^ ((gt >> 4) & 15)) * 8;

  const int swzk = l31 & 7, swzv = l31 & 15;
  const int bb = bh >> 4, h = bh & 15;

  f32x16 o0 = {}, o1 = {};
  float m = -3.0e38f, lsum = 0.f;

  auto sched = [&](int g, int it, int& j, int& t) -> bool {
    if (g) { j = jB; t = it; return true; }
    if (it <= p) { j = jA; t = it; return true; }
    if (it <= 7) { j = jB; t = 16 - it; return true; }
    return false;
  };
  auto STAGE = [&](int t, int buf) {
    bf16* kd = &Ks[grp][buf][gt * 8];
    bf16* vd = &Vs[grp][buf][gt * 8];
    const bf16* ksr = gk + (size_t)t * (128 * 64);
    const bf16* vsr = gv + t * 128;
#pragma unroll
    for (int c = 0; c < 4; c++) {
      async16(ksr + c * (32 * 64), kd + c * 2048);
      async16(vsr + c * (16 * 2048), vd + c * 2048);
    }
  };

  STAGE(0, 0);

  for (int it = 0; it < 9; ++it) {
    const int buf = it & 1;
    __syncthreads();
    {
      int jn, tn;
      if (it + 1 < 9 && sched(grp, it + 1, jn, tn)) STAGE(tn, buf ^ 1);
    }
    int j, t;
    const bool live = sched(grp, it, j, t);
    if (live) {
      const int q = j * 128 + qs * 32 + l31;
      bf16x8 aq[4];
#pragma unroll
      for (int ds = 0; ds < 4; ds++)
        aq[ds] = *(const bf16x8*)(Qb + q * 64 + ds * 16 + hi * 8);
      const bf16* Kc = Ks[grp][buf];
      const bf16* Vc = Vs[grp][buf];

      f32x16 s[4] = {};
      __builtin_amdgcn_s_setprio(1);
#pragma unroll
      for (int nf = 0; nf < 4; nf++) {
        const int row = nf * 32 + l31;
#pragma unroll
        for (int ds = 0; ds < 4; ds++) {
          bf16x8 kf = *(const bf16x8*)(Kc + row * 64 + (((ds * 2 + hi) ^ swzk) << 3));
          s[nf] = __builtin_amdgcn_mfma_f32_32x32x16_bf16(kf, aq[ds], s[nf], 0, 0, 0);
        }
      }
      __builtin_amdgcn_s_setprio(0);

      if (t == j) {
#pragma unroll
        for (int nf = 0; nf < 4; nf++)
#pragma unroll
          for (int r = 0; r < 16; r++) {
            const int kt = t * 128 + nf * 32 + (r & 3) + 8 * (r >> 2) + 4 * hi;
            if (kt > q) s[nf][r] = -3.0e38f;
          }
      }

      float red[8];
#pragma unroll
      for (int r = 0; r < 8; r++)
        red[r] = fmaxf(fmaxf(s[0][r], s[0][r + 8]), fmaxf(s[1][r], s[1][r + 8]));
#pragma unroll
      for (int r = 0; r < 8; r++)
        red[r] = fmaxf(red[r], fmaxf(fmaxf(s[2][r], s[2][r + 8]),
                                     fmaxf(s[3][r], s[3][r + 8])));
#pragma unroll
      for (int st = 4; st >= 1; st >>= 1)
#pragma unroll
        for (int r = 0; r < 4; r++)
          if (r < st) red[r] = fmaxf(red[r], red[r + st]);
      float mx = red[0];
      mx = fmaxf(mx, __shfl_xor(mx, 32));
      if (!__all(mx - m <= 8.0f)) {              // defer-max (T13)
        const float mnew = fmaxf(m, mx);
        const float alpha = __builtin_amdgcn_exp2f(m - mnew);
        m = mnew; lsum *= alpha;
#pragma unroll
        for (int r = 0; r < 16; r++) { o0[r] *= alpha; o1[r] *= alpha; }
      }
      float tsp[4] = {0.f, 0.f, 0.f, 0.f};
      unsigned w[4][8];
#pragma unroll
      for (int nf = 0; nf < 4; nf++)
#pragma unroll
        for (int k = 0; k < 8; k++) {
          const float pa = __builtin_amdgcn_exp2f(s[nf][2 * k] - m);
          const float pc = __builtin_amdgcn_exp2f(s[nf][2 * k + 1] - m);
          tsp[k & 3] += pa + pc;
          w[nf][k] = pk(pa, pc);
        }
      float ts = (tsp[0] + tsp[1]) + (tsp[2] + tsp[3]);
      ts += __shfl_xor(ts, 32);
      lsum += ts;

      __builtin_amdgcn_s_setprio(1);
#pragma unroll
      for (int nf = 0; nf < 4; nf++) {
#pragma unroll
        for (int hh = 0; hh < 2; hh++) {
          const unsigned w0 = w[nf][hh * 4 + 0], w1 = w[nf][hh * 4 + 1];
          const unsigned w2 = w[nf][hh * 4 + 2], w3 = w[nf][hh * 4 + 3];
          const unsigned rx = (unsigned)__shfl_xor((int)(hi ? w0 : w2), 32);
          const unsigned ry = (unsigned)__shfl_xor((int)(hi ? w1 : w3), 32);
          u32x4 pw;
          pw[0] = hi ? rx : w0;
          pw[1] = hi ? ry : w1;
          pw[2] = hi ? w2 : rx;
          pw[3] = hi ? w3 : ry;
          const bf16x8 pb = __builtin_bit_cast(bf16x8, pw);
          const int c = nf * 2 + hh;
          const bf16x8 vf0 = *(const bf16x8*)(Vc + l31 * 128 +
                                              (((c * 2 + hi) ^ swzv) << 3));
          o0 = __builtin_amdgcn_mfma_f32_32x32x16_bf16(vf0, pb, o0, 0, 0, 0);
          const bf16x8 vf1 = *(const bf16x8*)(Vc + (32 + l31) * 128 +
                                              (((c * 2 + hi) ^ swzv) << 3));
          o1 = __builtin_amdgcn_mfma_f32_32x32x16_bf16(vf1, pb, o1, 0, 0, 0);
        }
      }
      __builtin_amdgcn_s_setprio(0);
    }

    if (grp == 0 && it == p) {                   // own tile complete: store + reset
      const float inv = 1.0f / lsum;
      const int q = jA * 128 + qs * 32 + l31;
      bf16* Op = O + (size_t)(bb * 2048 + q) * 1024 + h * 64;
#pragma unroll
      for (int g = 0; g < 4; g++) {
        bf16x4 v0, v1;
#pragma unroll
        for (int k2 = 0; k2 < 4; k2++) {
          v0[k2] = (bf16)(o0[g * 4 + k2] * inv);
          v1[k2] = (bf16)(o1[g * 4 + k2] * inv);
        }
        *(bf16x4*)(Op + g * 8 + hi * 4) = v0;
        *(bf16x4*)(Op + 32 + g * 8 + hi * 4) = v1;
      }
      m = -3.0e38f; lsum = 0.f;
#pragma unroll
      for (int r = 0; r < 16; r++) { o0[r] = 0.f; o1[r] = 0.f; }
    }
  }

  // ---- merge A's P'-partial into B's state; B stores q-tile jB ----
  __syncthreads();
  float* oX = (float*)Vs;
  float* mX = (float*)Ks;
  const int slot = qs * 64 + lane;
  if (grp == 0) {
#pragma unroll
    for (int r = 0; r < 16; r++) {
      oX[r * 256 + slot] = o0[r];
      oX[(16 + r) * 256 + slot] = o1[r];
    }
    mX[slot] = m;
    mX[256 + slot] = lsum;
  }
  __syncthreads();
  if (grp == 1) {
    const float mB = mX[slot], lB = mX[256 + slot];
    const float m12 = fmaxf(m, mB);
    const float aA = __builtin_amdgcn_exp2f(m - m12);
    const float aB = __builtin_amdgcn_exp2f(mB - m12);
    const float inv = 1.0f / (lsum * aA + lB * aB);
    const int q = jB * 128 + qs * 32 + l31;
    bf16* Op = O + (size_t)(bb * 2048 + q) * 1024 + h * 64;
#pragma unroll
    for (int g = 0; g < 4; g++) {
      bf16x4 v0, v1;
#pragma unroll
      for (int k2 = 0; k2 < 4; k2++) {
        const int r = g * 4 + k2;
        v0[k2] = (bf16)((o0[r] * aA + oX[r * 256 + slot] * aB) * inv);
        v1[k2] = (bf16)((o1[r] * aA + oX[(16 + r) * 256 + slot] * aB) * inv);
      }
      *(bf16x4*)(Op + g * 8 + hi * 4) = v0;
      *(bf16x4*)(Op + 32 + g * 8 + hi * 4) = v1;
    }
  }
}

// ---------------------------------------------------------------- launch
extern "C" void kernel_launch(void* const* d_in, const int* in_sizes, int n_in,
                              void* d_out, int out_size, void* d_ws, size_t ws_size,
                              hipStream_t stream) {
  const float* x     = (const float*)d_in[0];
  const float* Wqkv  = (const float*)d_in[1];
  const float* bqkv  = (const float*)d_in[2];
  const float* Wproj = (const float*)d_in[3];
  const float* bproj = (const float*)d_in[4];
  float* out = (float*)d_out;

  char* p = (char*)d_ws;
  bf16* xbf    = (bf16*)p; p += (size_t)M_ * C_ * 2;     // 8 MB
  bf16* wqkvT  = (bf16*)p; p += (size_t)NQKV * C_ * 2;   // 6 MB
  bf16* wprojT = (bf16*)p; p += (size_t)C_ * C_ * 2;     // 2 MB
  bf16* Qb     = (bf16*)p; p += (size_t)M_ * C_ * 2;     // 8 MB
  bf16* Kb     = (bf16*)p; p += (size_t)M_ * C_ * 2;     // 8 MB
  bf16* Vtb    = (bf16*)p; p += (size_t)M_ * C_ * 2;     // 8 MB
  bf16* AO     = (bf16*)p;                               // 8 MB (total 48 MB)

  prep_k<<<8192, 256, 0, stream>>>(x, xbf, Wqkv, wqkvT, Wproj, wprojT);

  // QKV: 128x128, grid 32x24 = 768 = 3/CU, T1 swizzle (chunk 96/XCD)
  gemm_k<0, 128, 128, 3, 32, 768><<<dim3(32, 24), 256, 0, stream>>>(
      xbf, wqkvT, bqkv, nullptr, Qb, Kb, Vtb);

  attn_k<<<256, 512, 0, stream>>>(Qb, Kb, Vtb, AO);

  // proj: 64x64, grid 64x16 = 1024 = 4/CU, T1 swizzle (chunk 128/XCD)
  gemm_k<1, 64, 64, 4, 64, 1024><<<dim3(64, 16), 256, 0, stream>>>(
      AO, wprojT, bproj, out, nullptr, nullptr, nullptr);
}

// Round 12
// 161.222 us; speedup vs baseline: 1.0522x; 1.0522x over previous
//
#include <hip/hip_runtime.h>

#define B_    2
#define T_    2048
#define C_    1024
#define H_    16
#define DH_   64
#define M_    (B_ * T_)        // 4096 tokens
#define NQKV  (3 * C_)         // 3072

typedef __bf16 bf16;
typedef __bf16 bf16x2 __attribute__((ext_vector_type(2)));
typedef __bf16 bf16x4 __attribute__((ext_vector_type(4)));
typedef __bf16 bf16x8 __attribute__((ext_vector_type(8)));
typedef float  f32x4  __attribute__((ext_vector_type(4)));
typedef float  f32x16 __attribute__((ext_vector_type(16)));
typedef unsigned u32x4 __attribute__((ext_vector_type(4)));

// async global->LDS, 16B per lane (global_load_lds_dwordx4).
__device__ __forceinline__ void async16(const void* g, void* l) {
  __builtin_amdgcn_global_load_lds(
      (const __attribute__((address_space(1))) void*)g,
      (__attribute__((address_space(3))) void*)l, 16, 0, 0);
}

// pack two f32 -> one dword of 2 bf16 (lo in bits 0-15)
__device__ __forceinline__ unsigned pk(float a, float b) {
  bf16x2 t; t[0] = (bf16)a; t[1] = (bf16)b;
  return __builtin_bit_cast(unsigned, t);
}

// ---------------------------------------------------------------- fused prep
__global__ __launch_bounds__(256) void prep_k(
    const float* __restrict__ x, bf16* __restrict__ xbf,
    const float* __restrict__ Wqkv, bf16* __restrict__ wqkvT,
    const float* __restrict__ Wproj, bf16* __restrict__ wprojT) {
  __shared__ float tile[32][33];
  const int bid = blockIdx.x;
  if (bid < 4096) {                              // ---- cvt x
    const int i = (bid * 256 + threadIdx.x) * 4;
    float4 v = *(const float4*)(x + i);
    bf16x4 o;
    o[0] = (bf16)v.x; o[1] = (bf16)v.y; o[2] = (bf16)v.z; o[3] = (bf16)v.w;
    *(bf16x4*)(xbf + i) = o;
    return;
  }
  const float* in; bf16* out; int R, C, cb, rb;
  if (bid < 4096 + 3072) {                       // ---- Wqkv [1024 x 3072]
    const int b = bid - 4096;
    in = Wqkv; out = wqkvT; R = 1024; C = 3072; cb = b % 96; rb = b / 96;
  } else {                                       // ---- Wproj [1024 x 1024]
    const int b = bid - 7168;
    in = Wproj; out = wprojT; R = 1024; C = 1024; cb = b & 31; rb = b >> 5;
  }
  const int c0 = cb * 32, r0 = rb * 32;
  const int tx = threadIdx.x & 31, ty = threadIdx.x >> 5;
#pragma unroll
  for (int j = 0; j < 4; j++)
    tile[ty + j * 8][tx] = in[(size_t)(r0 + ty + j * 8) * C + c0 + tx];
  __syncthreads();
#pragma unroll
  for (int j = 0; j < 4; j++)
    out[(size_t)(c0 + ty + j * 8) * R + r0 + tx] = (bf16)tile[tx][ty + j * 8];
}

// ---------------------------------------------------------------- GEMM
// (r9 config restored — r11's T1 XCD swizzle measured −2% on these
// L3-resident inputs, matching the catalog caveat.) C[M,N] = A * Bt^T (+bias).
template <int EPI, int BM, int BN, int MW>
__global__ __launch_bounds__(256, MW) void gemm_k(
    const bf16* __restrict__ A, const bf16* __restrict__ Bt,
    const float* __restrict__ bias, float* __restrict__ outF,
    bf16* __restrict__ qb, bf16* __restrict__ kb, bf16* __restrict__ vtb) {
  constexpr int K = 1024;
  constexpr int MI = BM / 32;
  constexpr int NJ = BN / 32;
  __shared__ alignas(16) bf16 As[BM * 64];
  __shared__ alignas(16) bf16 Bs[BN * 64];
  const int tid = threadIdx.x;
  const int lane = tid & 63, wv = tid >> 6;
  const int l15 = lane & 15, quad = lane >> 4;
  const int wm = (wv >> 1) * (BM / 2), wn = (wv & 1) * (BN / 2);
  const int m0 = blockIdx.x * BM, n0 = blockIdx.y * BN;

  f32x4 acc[MI][NJ] = {};

  const int srow = tid >> 3;
  const int sgb = ((tid & 7) ^ (srow & 7)) * 8;
  const bf16* ga = A + (size_t)(m0 + srow) * K + sgb;
  const bf16* gb = Bt + (size_t)(n0 + srow) * K + sgb;
  const int swz = l15 & 7;

  for (int it = 0; it < K / 64; ++it) {
    const int k0 = it * 64;
#pragma unroll
    for (int c = 0; c < BM / 32; c++)
      async16(ga + k0 + (size_t)(c * 32) * K, As + tid * 8 + c * 2048);
#pragma unroll
    for (int c = 0; c < BN / 32; c++)
      async16(gb + k0 + (size_t)(c * 32) * K, Bs + tid * 8 + c * 2048);
    __syncthreads();
    bf16x8 af[2][MI], bfr[2][NJ];
#pragma unroll
    for (int kk = 0; kk < 2; kk++) {
#pragma unroll
      for (int i = 0; i < MI; i++)
        af[kk][i] = *(const bf16x8*)(As + (wm + i * 16 + l15) * 64 +
                                     (((kk * 4 + quad) ^ swz) << 3));
#pragma unroll
      for (int j = 0; j < NJ; j++)
        bfr[kk][j] = *(const bf16x8*)(Bs + (wn + j * 16 + l15) * 64 +
                                      (((kk * 4 + quad) ^ swz) << 3));
    }
#pragma unroll
    for (int kk = 0; kk < 2; kk++)
#pragma unroll
      for (int i = 0; i < MI; i++)
#pragma unroll
        for (int j = 0; j < NJ; j++)
          acc[i][j] = __builtin_amdgcn_mfma_f32_16x16x32_bf16(
              af[kk][i], bfr[kk][j], acc[i][j], 0, 0, 0);
    __syncthreads();
  }

#pragma unroll
  for (int i = 0; i < MI; i++) {
#pragma unroll
    for (int j = 0; j < NJ; j++) {
      const int gcol = n0 + wn + j * 16 + l15;
      const float bv = bias[gcol];
      const int trow = m0 + wm + i * 16 + quad * 4;
      if constexpr (EPI == 0) {
        const int which = gcol >> 10;
        const int hn = gcol & 1023;
        const int h = hn >> 6, d = hn & 63;
        const int bb = trow >> 11, t = trow & 2047;
        const int head = bb * 16 + h;
        if (which == 0) {
#pragma unroll
          for (int r = 0; r < 4; r++)
            qb[head * 131072 + (t + r) * 64 + d] =
                (bf16)((acc[i][j][r] + bv) * 0.1803368801f); // 1/8 * log2(e)
        } else if (which == 1) {
#pragma unroll
          for (int r = 0; r < 4; r++)
            kb[head * 131072 + (t + r) * 64 + d] = (bf16)(acc[i][j][r] + bv);
        } else {
          bf16x4 pv;
#pragma unroll
          for (int r = 0; r < 4; r++) pv[r] = (bf16)(acc[i][j][r] + bv);
          *(bf16x4*)(vtb + head * 131072 + d * 2048 + t) = pv;
        }
      } else {
#pragma unroll
        for (int r = 0; r < 4; r++)
          outF[(size_t)(trow + r) * 1024 + gcol] = acc[i][j][r] + bv;
      }
    }
  }
}

// ---------------------------------------------------------------- flash attention
// (r10 uniform-wall pair blocks + r12 aq-hoist.) Five structural variants all
// measured 45.3-47.4us with every pipe <35% — structure frozen. r12 change:
// aq was re-loaded from GLOBAL inside every iteration (~200-900cy latency at
// the head of each iter's QK chain). Each thread only ever needs TWO q-rows
// (tile jA, tile jB) -> hoist both fragment sets to registers pre-loop
// (+16 VGPR, no spill at 8 waves/CU) and select per-iter with branchless
// cndmask (~20cy, no memory latency).
__global__ __launch_bounds__(512, 2) void attn_k(const bf16* __restrict__ Q,
                                                 const bf16* __restrict__ K,
                                                 const bf16* __restrict__ Vt,
                                                 bf16* __restrict__ O) {
  __shared__ alignas(16) bf16 Ks[2][2][128 * 64]; // [grp][buf][kt][d]  64KB
  __shared__ alignas(16) bf16 Vs[2][2][64 * 128]; // [grp][buf][d][kt]  64KB
  const int tid = threadIdx.x, lane = tid & 63, wv = tid >> 6;  // wv 0..7
  const int l31 = lane & 31, hi = lane >> 5;
  const int grp = wv >> 2, qs = wv & 3;          // group / q sub-block
  const int gt = tid & 255;                      // intra-group thread

  const int b = blockIdx.x;                      // 0..255
  const int bh = (b & 7) | (((b >> 3) & 3) << 3);  // head 0..31, b&7 = XCD
  const int p = b >> 5;                          // pair index 0..7
  const int jA = p, jB = 15 - p;

  const bf16* Qb = Q + (size_t)bh * 131072;
  const bf16* Kb = K + (size_t)bh * 131072;
  const bf16* Vb = Vt + (size_t)bh * 131072;

  const bf16* gk = Kb + (gt >> 3) * 64 + ((gt & 7) ^ ((gt >> 3) & 7)) * 8;
  const bf16* gv = Vb + (gt >> 4) * 2048 + ((gt & 15) ^ ((gt >> 4) & 15)) * 8;

  const int swzk = l31 & 7, swzv = l31 & 15;
  const int bb = bh >> 4, h = bh & 15;

  // r12: hoist Q fragments for BOTH q-tiles this thread can touch
  const int qArow = jA * 128 + qs * 32 + l31;
  const int qBrow = jB * 128 + qs * 32 + l31;
  bf16x8 aqA[4], aqB[4];
#pragma unroll
  for (int ds = 0; ds < 4; ds++) {
    aqA[ds] = *(const bf16x8*)(Qb + qArow * 64 + ds * 16 + hi * 8);
    aqB[ds] = *(const bf16x8*)(Qb + qBrow * 64 + ds * 16 + hi * 8);
  }

  f32x16 o0 = {}, o1 = {};
  float m = -3.0e38f, lsum = 0.f;

  auto sched = [&](int g, int it, int& j, int& t) -> bool {
    if (g) { j = jB; t = it; return true; }
    if (it <= p) { j = jA; t = it; return true; }
    if (it <= 7) { j = jB; t = 16 - it; return true; }
    return false;
  };
  auto STAGE = [&](int t, int buf) {
    bf16* kd = &Ks[grp][buf][gt * 8];
    bf16* vd = &Vs[grp][buf][gt * 8];
    const bf16* ksr = gk + (size_t)t * (128 * 64);
    const bf16* vsr = gv + t * 128;
#pragma unroll
    for (int c = 0; c < 4; c++) {
      async16(ksr + c * (32 * 64), kd + c * 2048);
      async16(vsr + c * (16 * 2048), vd + c * 2048);
    }
  };

  STAGE(0, 0);

  for (int it = 0; it < 9; ++it) {
    const int buf = it & 1;
    __syncthreads();
    {
      int jn, tn;
      if (it + 1 < 9 && sched(grp, it + 1, jn, tn)) STAGE(tn, buf ^ 1);
    }
    int j, t;
    const bool live = sched(grp, it, j, t);
    if (live) {
      const bool useA = (j == jA) && (grp == 0);
      const int q = useA ? qArow : qBrow;
      const bf16* Kc = Ks[grp][buf];
      const bf16* Vc = Vs[grp][buf];

      f32x16 s[4] = {};
      __builtin_amdgcn_s_setprio(1);
#pragma unroll
      for (int nf = 0; nf < 4; nf++) {
        const int row = nf * 32 + l31;
#pragma unroll
        for (int ds = 0; ds < 4; ds++) {
          const bf16x8 aq = useA ? aqA[ds] : aqB[ds];   // branchless select
          bf16x8 kf = *(const bf16x8*)(Kc + row * 64 + (((ds * 2 + hi) ^ swzk) << 3));
          s[nf] = __builtin_amdgcn_mfma_f32_32x32x16_bf16(kf, aq, s[nf], 0, 0, 0);
        }
      }
      __builtin_amdgcn_s_setprio(0);

      if (t == j) {
#pragma unroll
        for (int nf = 0; nf < 4; nf++)
#pragma unroll
          for (int r = 0; r < 16; r++) {
            const int kt = t * 128 + nf * 32 + (r & 3) + 8 * (r >> 2) + 4 * hi;
            if (kt > q) s[nf][r] = -3.0e38f;
          }
      }

      float red[8];
#pragma unroll
      for (int r = 0; r < 8; r++)
        red[r] = fmaxf(fmaxf(s[0][r], s[0][r + 8]), fmaxf(s[1][r], s[1][r + 8]));
#pragma unroll
      for (int r = 0; r < 8; r++)
        red[r] = fmaxf(red[r], fmaxf(fmaxf(s[2][r], s[2][r + 8]),
                                     fmaxf(s[3][r], s[3][r + 8])));
#pragma unroll
      for (int st = 4; st >= 1; st >>= 1)
#pragma unroll
        for (int r = 0; r < 4; r++)
          if (r < st) red[r] = fmaxf(red[r], red[r + st]);
      float mx = red[0];
      mx = fmaxf(mx, __shfl_xor(mx, 32));
      if (!__all(mx - m <= 8.0f)) {              // defer-max (T13)
        const float mnew = fmaxf(m, mx);
        const float alpha = __builtin_amdgcn_exp2f(m - mnew);
        m = mnew; lsum *= alpha;
#pragma unroll
        for (int r = 0; r < 16; r++) { o0[r] *= alpha; o1[r] *= alpha; }
      }
      float tsp[4] = {0.f, 0.f, 0.f, 0.f};
      unsigned w[4][8];
#pragma unroll
      for (int nf = 0; nf < 4; nf++)
#pragma unroll
        for (int k = 0; k < 8; k++) {
          const float pa = __builtin_amdgcn_exp2f(s[nf][2 * k] - m);
          const float pc = __builtin_amdgcn_exp2f(s[nf][2 * k + 1] - m);
          tsp[k & 3] += pa + pc;
          w[nf][k] = pk(pa, pc);
        }
      float ts = (tsp[0] + tsp[1]) + (tsp[2] + tsp[3]);
      ts += __shfl_xor(ts, 32);
      lsum += ts;

      __builtin_amdgcn_s_setprio(1);
#pragma unroll
      for (int nf = 0; nf < 4; nf++) {
#pragma unroll
        for (int hh = 0; hh < 2; hh++) {
          const unsigned w0 = w[nf][hh * 4 + 0], w1 = w[nf][hh * 4 + 1];
          const unsigned w2 = w[nf][hh * 4 + 2], w3 = w[nf][hh * 4 + 3];
          const unsigned rx = (unsigned)__shfl_xor((int)(hi ? w0 : w2), 32);
          const unsigned ry = (unsigned)__shfl_xor((int)(hi ? w1 : w3), 32);
          u32x4 pw;
          pw[0] = hi ? rx : w0;
          pw[1] = hi ? ry : w1;
          pw[2] = hi ? w2 : rx;
          pw[3] = hi ? w3 : ry;
          const bf16x8 pb = __builtin_bit_cast(bf16x8, pw);
          const int c = nf * 2 + hh;
          const bf16x8 vf0 = *(const bf16x8*)(Vc + l31 * 128 +
                                              (((c * 2 + hi) ^ swzv) << 3));
          o0 = __builtin_amdgcn_mfma_f32_32x32x16_bf16(vf0, pb, o0, 0, 0, 0);
          const bf16x8 vf1 = *(const bf16x8*)(Vc + (32 + l31) * 128 +
                                              (((c * 2 + hi) ^ swzv) << 3));
          o1 = __builtin_amdgcn_mfma_f32_32x32x16_bf16(vf1, pb, o1, 0, 0, 0);
        }
      }
      __builtin_amdgcn_s_setprio(0);
    }

    if (grp == 0 && it == p) {                   // own tile complete: store + reset
      const float inv = 1.0f / lsum;
      bf16* Op = O + (size_t)(bb * 2048 + qArow) * 1024 + h * 64;
#pragma unroll
      for (int g = 0; g < 4; g++) {
        bf16x4 v0, v1;
#pragma unroll
        for (int k2 = 0; k2 < 4; k2++) {
          v0[k2] = (bf16)(o0[g * 4 + k2] * inv);
          v1[k2] = (bf16)(o1[g * 4 + k2] * inv);
        }
        *(bf16x4*)(Op + g * 8 + hi * 4) = v0;
        *(bf16x4*)(Op + 32 + g * 8 + hi * 4) = v1;
      }
      m = -3.0e38f; lsum = 0.f;
#pragma unroll
      for (int r = 0; r < 16; r++) { o0[r] = 0.f; o1[r] = 0.f; }
    }
  }

  // ---- merge A's P'-partial into B's state; B stores q-tile jB ----
  __syncthreads();
  float* oX = (float*)Vs;
  float* mX = (float*)Ks;
  const int slot = qs * 64 + lane;
  if (grp == 0) {
#pragma unroll
    for (int r = 0; r < 16; r++) {
      oX[r * 256 + slot] = o0[r];
      oX[(16 + r) * 256 + slot] = o1[r];
    }
    mX[slot] = m;
    mX[256 + slot] = lsum;
  }
  __syncthreads();
  if (grp == 1) {
    const float mB = mX[slot], lB = mX[256 + slot];
    const float m12 = fmaxf(m, mB);
    const float aA = __builtin_amdgcn_exp2f(m - m12);
    const float aB = __builtin_amdgcn_exp2f(mB - m12);
    const float inv = 1.0f / (lsum * aA + lB * aB);
    bf16* Op = O + (size_t)(bb * 2048 + qBrow) * 1024 + h * 64;
#pragma unroll
    for (int g = 0; g < 4; g++) {
      bf16x4 v0, v1;
#pragma unroll
      for (int k2 = 0; k2 < 4; k2++) {
        const int r = g * 4 + k2;
        v0[k2] = (bf16)((o0[r] * aA + oX[r * 256 + slot] * aB) * inv);
        v1[k2] = (bf16)((o1[r] * aA + oX[(16 + r) * 256 + slot] * aB) * inv);
      }
      *(bf16x4*)(Op + g * 8 + hi * 4) = v0;
      *(bf16x4*)(Op + 32 + g * 8 + hi * 4) = v1;
    }
  }
}

// ---------------------------------------------------------------- launch
extern "C" void kernel_launch(void* const* d_in, const int* in_sizes, int n_in,
                              void* d_out, int out_size, void* d_ws, size_t ws_size,
                              hipStream_t stream) {
  const float* x     = (const float*)d_in[0];
  const float* Wqkv  = (const float*)d_in[1];
  const float* bqkv  = (const float*)d_in[2];
  const float* Wproj = (const float*)d_in[3];
  const float* bproj = (const float*)d_in[4];
  float* out = (float*)d_out;

  char* p = (char*)d_ws;
  bf16* xbf    = (bf16*)p; p += (size_t)M_ * C_ * 2;     // 8 MB
  bf16* wqkvT  = (bf16*)p; p += (size_t)NQKV * C_ * 2;   // 6 MB
  bf16* wprojT = (bf16*)p; p += (size_t)C_ * C_ * 2;     // 2 MB
  bf16* Qb     = (bf16*)p; p += (size_t)M_ * C_ * 2;     // 8 MB
  bf16* Kb     = (bf16*)p; p += (size_t)M_ * C_ * 2;     // 8 MB
  bf16* Vtb    = (bf16*)p; p += (size_t)M_ * C_ * 2;     // 8 MB
  bf16* AO     = (bf16*)p;                               // 8 MB (total 48 MB)

  prep_k<<<8192, 256, 0, stream>>>(x, xbf, Wqkv, wqkvT, Wproj, wprojT);

  // QKV: 128x128 tile, grid 32x24 = 768 blocks = 3/CU (MW=3 -> VGPR<=170)
  gemm_k<0, 128, 128, 3><<<dim3(M_ / 128, NQKV / 128), 256, 0, stream>>>(
      xbf, wqkvT, bqkv, nullptr, Qb, Kb, Vtb);

  attn_k<<<256, 512, 0, stream>>>(Qb, Kb, Vtb, AO);

  // proj: 64x64 tile, grid 64x16 = 1024 blocks = 4/CU (MW=4 -> VGPR<=128)
  gemm_k<1, 64, 64, 4><<<dim3(M_ / 64, C_ / 64), 256, 0, stream>>>(
      AO, wprojT, bproj, out, nullptr, nullptr, nullptr);
}